// Round 10
// baseline (210.835 us; speedup 1.0000x reference)
//
#include <hip/hip_runtime.h>
#include <cstdint>
#include <cstddef>

#define NUM_LAYERS 20
#define HID 1024
#define M_TOTAL 8192

typedef __attribute__((ext_vector_type(8))) short bf16x8;
typedef __attribute__((ext_vector_type(4))) float floatx4;
typedef __attribute__((ext_vector_type(4))) float f32x4;
typedef __attribute__((ext_vector_type(8))) unsigned short u16x8;

typedef __attribute__((address_space(1))) unsigned int as1_u32;
typedef __attribute__((address_space(3))) unsigned int as3_u32;

__device__ __forceinline__ unsigned short f2bf(float f) {
  union { float f; unsigned int u; } v; v.f = f;
  unsigned int r = v.u + 0x7fffu + ((v.u >> 16) & 1u);  // RNE
  return (unsigned short)(r >> 16);
}

__device__ __forceinline__ u16x8 pack8(f32x4 a, f32x4 b) {
  u16x8 o;
  o[0] = f2bf(a[0]); o[1] = f2bf(a[1]); o[2] = f2bf(a[2]); o[3] = f2bf(a[3]);
  o[4] = f2bf(b[0]); o[5] = f2bf(b[1]); o[6] = f2bf(b[2]); o[7] = f2bf(b[3]);
  return o;
}

// async global->LDS, 16B/lane; LDS ptr must be wave-uniform base (HW adds lane*16)
__device__ __forceinline__ void load16_lds(const void* g, void* l) {
  __builtin_amdgcn_global_load_lds(
      reinterpret_cast<as1_u32*>(reinterpret_cast<uintptr_t>(g)),
      reinterpret_cast<as3_u32*>(reinterpret_cast<uintptr_t>(l)),
      16, 0, 0);
}

// ---- Kernel 1: conv_w 20-layer sum -> bf16 wb [N][K] row-major (proven ~13us).
// Also zeroes the ssq/counter workspace the fused GEMM+norm needs each launch
// (harness re-poisons d_ws between iterations).
__global__ __launch_bounds__(256, 1) void wsum_kernel(const float* __restrict__ w,
                                                      unsigned short* __restrict__ wb,
                                                      float* __restrict__ ssq,
                                                      unsigned int* __restrict__ cnt) {
  const int b = blockIdx.x;
  const int t = threadIdx.x;
  if (b < 32) ssq[b * 256 + t] = 0.0f;          // 8192 row-ssq accumulators
  if (b == 32 && t < 64) cnt[t] = 0u;           // 64 per-mb completion counters
  const int P = b * 256 + t;  // ushort8 output index
  const f32x4* p = reinterpret_cast<const f32x4*>(w);
  f32x4 va[NUM_LAYERS], vb[NUM_LAYERS];
#pragma unroll
  for (int l = 0; l < NUM_LAYERS; ++l) {
    const f32x4* pl = p + (size_t)l * (HID * HID / 4) + (size_t)2 * P;
    va[l] = __builtin_nontemporal_load(pl);
    vb[l] = __builtin_nontemporal_load(pl + 1);
  }
  f32x4 s0 = va[0], s1 = vb[0];
#pragma unroll
  for (int l = 1; l < NUM_LAYERS; ++l) { s0 += va[l]; s1 += vb[l]; }
  reinterpret_cast<u16x8*>(wb)[P] = pack8(s0, s1);
}

// ---- Kernel 2: fused GEMM + RMSNorm. C never exists in memory. ----
// GEMM core = round-8 best (182.3 us): 128x128 tile, BK=64, 4 waves (2Mx2N),
// double-buffered LDS, ONE plain __syncthreads per K-step (round-9's counted
// vmcnt reverted: neutral-to-negative, regime-gated to 8-phase schedules).
// New epilogue instead of bf16 C store + separate rmsnorm kernel:
//   1) row-ssq partials from acc (16-lane shfl reduce)
//   2) one fp32 atomicAdd per row (device-scope) + __threadfence
//   3) per-mb completion counter; all 8 nb-blocks spin until count==8.
//      SAFE: grid 512 = exactly 2 blocks/CU (LDS 64KB, VGPR<=256 via (256,2))
//      -> all blocks co-resident; atomics device-scope -> XCD-map-independent.
//   4) agent-scope reload of the 128 row sums -> LDS -> scale acc in-register
//      -> write fp32 out directly (32 MB, the only output traffic).
__global__ __launch_bounds__(256, 2) void gemm_norm_kernel(const float* __restrict__ x,
                                                           const unsigned short* __restrict__ B,
                                                           const float* __restrict__ nw,
                                                           float* __restrict__ out,
                                                           float* __restrict__ ssq,
                                                           unsigned int* __restrict__ cnt) {
  __shared__ unsigned short lA[2][128 * 64];  // 2 x 16 KiB
  __shared__ unsigned short lB[2][128 * 64];  // 2 x 16 KiB

  const int tid = threadIdx.x;
  const int lane = tid & 63;
  const int w = tid >> 6;      // wave 0..3
  const int wr = w >> 1;       // 0..1 -> M half
  const int wc = w & 1;        // 0..1 -> N half
  const int quad = lane >> 4;  // 0..3
  const int mrow = lane & 15;

  const int bid = blockIdx.x;
  const int mb = bid & 63;  // 64 M-tiles; same-A blocks cluster on one XCD
  const int nb = bid >> 6;  // 8 N-tiles
  const int m0 = mb * 128;
  const int n0 = nb * 128;

  // Staging: issue i covers row r = i*32 + (t>>3), logical 16B-slot (t&7) of
  // the 128 B row; physical slot = logical ^ (r&7)  (slot-XOR swizzle).
  const int srow = tid >> 3;
  const int skslot = tid & 7;
  const int sphys = skslot ^ (srow & 7);
  const unsigned short* gB = B + (size_t)(n0 + srow) * HID + sphys * 8;  // pre-swz src
  const float* gA = x + (size_t)(m0 + srow) * HID + skslot * 8;
  unsigned short* dA = &lA[0][0] + srow * 64 + sphys * 8;
  unsigned short* dB = &lB[0][0] + w * 512;  // wave-uniform

  floatx4 acc[4][4] = {};
  f32x4 Ar[8];

  const int offk0 = ((quad ^ (mrow & 7)) << 3);  // swizzled frag k-offset, kk=0
  const unsigned short* ra[4];
  const unsigned short* rb[4];
#pragma unroll
  for (int i = 0; i < 4; ++i)
    ra[i] = &lA[0][0] + (wr * 64 + i * 16 + mrow) * 64;
#pragma unroll
  for (int j = 0; j < 4; ++j)
    rb[j] = &lB[0][0] + (wc * 64 + j * 16 + mrow) * 64;

#define LOADA(k0)                                                              \
  {                                                                            \
    _Pragma("unroll") for (int i = 0; i < 4; ++i) {                            \
      const float* s = gA + (size_t)(i * 32) * HID + (k0);                     \
      Ar[2 * i]     = *reinterpret_cast<const f32x4*>(s);                      \
      Ar[2 * i + 1] = *reinterpret_cast<const f32x4*>(s + 4);                  \
    }                                                                          \
  }
#define STAGEB(bufofs, k0)                                                     \
  {                                                                            \
    _Pragma("unroll") for (int i = 0; i < 4; ++i)                              \
        load16_lds(gB + (size_t)(i * 32) * HID + (k0),                         \
                   dB + (bufofs) + i * 2048);                                  \
  }
#define WRITEA(bufofs)                                                         \
  {                                                                            \
    _Pragma("unroll") for (int i = 0; i < 4; ++i)                              \
        *reinterpret_cast<u16x8*>(dA + (bufofs) + i * 2048) =                  \
            pack8(Ar[2 * i], Ar[2 * i + 1]);                                   \
  }

  // Prologue: buffer 0 staged for t=0; A regs for t=1 in flight.
  LOADA(0);
  STAGEB(0, 0);
  WRITEA(0);
  LOADA(64);
  __syncthreads();

  for (int t = 0; t < 16; ++t) {
    const int cofs = (t & 1) << 13;
    const int nofs = cofs ^ 8192;

    bf16x8 af[2][4], bfr[2][4];
#pragma unroll
    for (int kk = 0; kk < 2; ++kk) {
      const int off = offk0 ^ (kk << 5);
#pragma unroll
      for (int i = 0; i < 4; ++i)
        af[kk][i] = *reinterpret_cast<const bf16x8*>(ra[i] + cofs + off);
#pragma unroll
      for (int j = 0; j < 4; ++j)
        bfr[kk][j] = *reinterpret_cast<const bf16x8*>(rb[j] + cofs + off);
    }

    if (t < 15) {
      STAGEB(nofs, (t + 1) * 64);
      WRITEA(nofs);
    }
    if (t < 14) LOADA((t + 2) * 64);

#pragma unroll
    for (int kk = 0; kk < 2; ++kk)
#pragma unroll
      for (int i = 0; i < 4; ++i)
#pragma unroll
        for (int j = 0; j < 4; ++j)
          acc[i][j] = __builtin_amdgcn_mfma_f32_16x16x32_bf16(af[kk][i], bfr[kk][j],
                                                              acc[i][j], 0, 0, 0);

    __syncthreads();
  }
#undef LOADA
#undef STAGEB
#undef WRITEA

  // ---- fused norm epilogue ----
  // C/D layout: thread's acc[i][j][r] = C[m0+wr*64+i*16+quad*4+r][n0+wc*64+j*16+mrow]
  float* red = reinterpret_cast<float*>(&lA[0][0]);  // reuse LDS: [2][128] floats

  // 1) per-row ssq partial over this thread's 4 cols, reduced across 16 mrows
  float ps[4][4];
#pragma unroll
  for (int i = 0; i < 4; ++i)
#pragma unroll
    for (int r = 0; r < 4; ++r) {
      float s = 0.f;
#pragma unroll
      for (int j = 0; j < 4; ++j) { float v = acc[i][j][r]; s += v * v; }
#pragma unroll
      for (int off = 1; off < 16; off <<= 1) s += __shfl_xor(s, off, 64);
      ps[i][r] = s;
    }
  if (mrow == 0) {
#pragma unroll
    for (int i = 0; i < 4; ++i)
#pragma unroll
      for (int r = 0; r < 4; ++r)
        red[wc * 128 + wr * 64 + i * 16 + quad * 4 + r] = ps[i][r];
  }
  __syncthreads();

  // 2) block-level row partial -> device atomicAdd (one per row)
  if (tid < 128) atomicAdd(&ssq[m0 + tid], red[tid] + red[128 + tid]);
  __threadfence();
  __syncthreads();

  // 3) completion counter + spin until all 8 nb-blocks of this mb are done
  if (tid == 0) {
    atomicAdd(&cnt[mb], 1u);
    while (__hip_atomic_load(&cnt[mb], __ATOMIC_ACQUIRE,
                             __HIP_MEMORY_SCOPE_AGENT) < 8u)
      __builtin_amdgcn_s_sleep(8);
  }
  __syncthreads();

  // 4) reload final row sums (agent scope -> L2-coherent), then scale+store
  if (tid < 128)
    red[tid] = __hip_atomic_load(&ssq[m0 + tid], __ATOMIC_RELAXED,
                                 __HIP_MEMORY_SCOPE_AGENT);
  __syncthreads();

  float nwv[4];
#pragma unroll
  for (int j = 0; j < 4; ++j) nwv[j] = nw[n0 + wc * 64 + j * 16 + mrow];

  // out = C * 32 * rsqrt(sum C^2 + 400*eps*H) * norm_w   (/20 folded; C raw dot)
#pragma unroll
  for (int i = 0; i < 4; ++i) {
#pragma unroll
    for (int r = 0; r < 4; ++r) {
      const int rloc = wr * 64 + i * 16 + quad * 4 + r;
      const float sc = 32.0f * rsqrtf(red[rloc] + 0.4096f);  // 0.4096 = eps*H*400
      float* orow = out + (size_t)(m0 + rloc) * HID + n0 + wc * 64 + mrow;
#pragma unroll
      for (int j = 0; j < 4; ++j)
        orow[j * 16] = acc[i][j][r] * sc * nwv[j];
    }
  }
}

extern "C" void kernel_launch(void* const* d_in, const int* in_sizes, int n_in,
                              void* d_out, int out_size, void* d_ws, size_t ws_size,
                              hipStream_t stream) {
  const float* x = (const float*)d_in[0];       // [2,4096,1024] fp32
  const float* conv_w = (const float*)d_in[1];  // [20,1024,1024] fp32
  const float* norm_w = (const float*)d_in[2];  // [1024] fp32
  float* out = (float*)d_out;                   // [2,4096,1024] fp32

  unsigned short* wb = (unsigned short*)d_ws;           // 2 MiB: summed W bf16 [N][K]
  float* ssq = (float*)(wb + (size_t)HID * HID);        // 32 KiB: row ssq accum
  unsigned int* cnt = (unsigned int*)(ssq + M_TOTAL);   // 256 B: per-mb counters

  wsum_kernel<<<512, 256, 0, stream>>>(conv_w, wb, ssq, cnt);
  gemm_norm_kernel<<<(M_TOTAL / 128) * (HID / 128), 256, 0, stream>>>(
      x, wb, norm_w, out, ssq, cnt);
}